// Round 11
// baseline (174.937 us; speedup 1.0000x reference)
//
#include <hip/hip_runtime.h>

// GATv2 x2 + LayerNorm, B=2 N=512 DIN=32 DH=DOUT=64 H=4. fp32 in/out.
// R21 = R20 + attn occupancy forcing. Unifying theory for six flat rounds:
// attn VGPR ~230 (measured R12) -> 2 waves/SIMD cap -> VALUBusy pinned at
// 25-29% everywhere; ds_read->use stalls have no co-resident wave to hide
// behind; NJC=8's extra blocks (R20) couldn't mount -> slight regression.
// Fix: __launch_bounds__(256,4) (128-VGPR cap) + de-registered aggregate
// (outer 8-group loop RUNTIME with SGPR-indexed readlane, inner 8 unrolled)
// so the cap holds without spill (~100 VGPR natural peak).

#define BB   2
#define NN   512
#define DIN  32
#define DH   64
#define HH   4
#define C1   256
#define C2   256
#define NJC  8     // j-chunks (64 j each)
#define LEPS 1e-5f

typedef unsigned long long u64;

__device__ __forceinline__ float bf_sum(float v) {
#pragma unroll
    for (int o = 32; o > 0; o >>= 1) v += __shfl_xor(v, o, 64);
    return v;
}

__device__ __forceinline__ void gload_lds16(const float* g, float* l) {
    __builtin_amdgcn_global_load_lds(
        (const __attribute__((address_space(1))) void*)g,
        (__attribute__((address_space(3))) void*)l, 16, 0, 0);
}

__device__ __forceinline__ float rdlane(float v, int l) {
    return __int_as_float(__builtin_amdgcn_readlane(__float_as_int(v), l));
}

// --- merged: blocks 0..1023 = proj1 (+fused sl/sr); 1024..1279 = mask ---
__global__ __launch_bounds__(256) void mp1_k(const float* __restrict__ x,
        const float* __restrict__ wl, const float* __restrict__ bl,
        const float* __restrict__ wr, const float* __restrict__ br,
        const float* __restrict__ att, const float* __restrict__ emb,
        float* __restrict__ xl, float* __restrict__ xr,
        float* __restrict__ sl, float* __restrict__ sr,
        u64* __restrict__ mask64) {
    __shared__ __align__(16) float s_ei[16][DH];
    __shared__ float ebuf[64][DH + 1];
    __shared__ float s_x[4][DIN];
    int bx = blockIdx.x;
    int t = threadIdx.x, lane = t & 63;

    if (bx >= 1024) {   // ---- mask role: 256 blocks, 16i x 64j tile ----
        int idx = bx - 1024, it = idx >> 3, jq = idx & 7;
        int iq = t >> 6, j0 = jq * 64;
        {
            int row = t >> 4, d4 = (t & 15) << 2;
            *(float4*)&s_ei[row][d4] = *(const float4*)(emb + (it * 16 + row) * DH + d4);
        }
#pragma unroll
        for (int k = 0; k < 4; k++) {
            int i2 = k * 256 + t, jl = i2 >> 4, d4 = (i2 & 15) << 2;
            float4 v = *(const float4*)(emb + (j0 + jl) * DH + d4);
            ebuf[jl][d4] = v.x; ebuf[jl][d4 + 1] = v.y;
            ebuf[jl][d4 + 2] = v.z; ebuf[jl][d4 + 3] = v.w;
        }
        __syncthreads();
        float acc[4] = {0.f, 0.f, 0.f, 0.f};
        for (int dc = 0; dc < 16; dc++) {
            int d = dc * 4;
            float e0 = ebuf[lane][d], e1 = ebuf[lane][d + 1];
            float e2 = ebuf[lane][d + 2], e3 = ebuf[lane][d + 3];
#pragma unroll
            for (int r = 0; r < 4; r++) {
                float4 iv = *(const float4*)&s_ei[iq * 4 + r][d];
                acc[r] += iv.x * e0 + iv.y * e1 + iv.z * e2 + iv.w * e3;
            }
        }
        int jg = j0 + lane;
#pragma unroll
        for (int r = 0; r < 4; r++) {
            int ig = it * 16 + iq * 4 + r;
            u64 bal = __ballot(acc[r] != 0.f || ig == jg);
            if (lane == 0) mask64[ig * 8 + jq] = bal;
        }
        return;
    }

    // ---- proj1 role ----
    int row0 = (bx >> 2) * 4, cq = bx & 3;
    if (t < 128) s_x[t >> 5][t & 31] = x[(row0 + (t >> 5)) * DIN + (t & 31)];
    __syncthreads();
    int cl = t & 127, half = t >> 7;
    int gc = cq * 128 + cl;
    const float* wbase; float bias; float* obase; float* sdst; int oc;
    if (gc < C1) { wbase = wl + gc; bias = bl[gc]; obase = xl; sdst = sl; oc = gc; }
    else         { wbase = wr + gc - C1; bias = br[gc - C1]; obase = xr; sdst = sr; oc = gc - C1; }
    int ra = half * 2, rb = ra + 1;
    float a0 = bias, a1 = bias;
#pragma unroll
    for (int k = 0; k < DIN; k++) {
        float wv = wbase[(size_t)k * C1];
        a0 += s_x[ra][k] * wv;
        a1 += s_x[rb][k] * wv;
    }
    obase[(size_t)(row0 + ra) * C1 + oc] = a0;
    obase[(size_t)(row0 + rb) * C1 + oc] = a1;
    float attv = att[oc];
    float s0 = bf_sum(attv * a0) * 0.6f;
    float s1 = bf_sum(attv * a1) * 0.6f;
    if (lane == 0) {
        int h = oc >> 6;
        int rwa = row0 + ra, rwb = row0 + rb;
        sdst[(h * BB + (rwa >> 9)) * NN + (rwa & 511)] = s0;
        sdst[(h * BB + (rwb >> 9)) * NN + (rwb & 511)] = s1;
    }
}

// --- combine partials + LN(g,be)+ReLU + proj2 + sl/sr ---
__global__ __launch_bounds__(256) void projln_k(const float* __restrict__ pagg,
        const float* __restrict__ plsum, const float* __restrict__ abias,
        const float* __restrict__ g, const float* __restrict__ be,
        const float* __restrict__ wl, const float* __restrict__ bl,
        const float* __restrict__ wr, const float* __restrict__ br,
        const float* __restrict__ att,
        float* __restrict__ xl, float* __restrict__ xr,
        float* __restrict__ sl, float* __restrict__ sr) {
    __shared__ __align__(16) float s_h[4][C1];
    int t = threadIdx.x, lane = t & 63, w = t >> 6;
    int row0 = blockIdx.x * 4, cq = blockIdx.y;
    {
        int rgb = row0 + w;
        int bb = rgb >> 9, ii = rgb & 511;
        int c4 = lane << 2, hh = lane >> 4;
        float vx = 0.f, vy = 0.f, vz = 0.f, vw = 0.f, l = 0.f;
#pragma unroll
        for (int jc = 0; jc < NJC; jc++) {
            float4 a = *(const float4*)(pagg + ((size_t)jc * BB * NN + rgb) * C1 + c4);
            vx += a.x; vy += a.y; vz += a.z; vw += a.w;
            l += plsum[((size_t)jc * HH * BB + hh * BB + bb) * NN + ii];
        }
        float inv = 1.f / l;
        float4 bi = *(const float4*)(abias + c4);
        vx = vx * inv + bi.x; vy = vy * inv + bi.y;
        vz = vz * inv + bi.z; vw = vw * inv + bi.w;
        float mu = bf_sum(vx + vy + vz + vw) * (1.f / 256.f);
        float dx = vx - mu, dy = vy - mu, dz = vz - mu, dw = vw - mu;
        float var = bf_sum(dx * dx + dy * dy + dz * dz + dw * dw) * (1.f / 256.f);
        float rs = rsqrtf(var + LEPS);
        float4 gv = *(const float4*)(g + c4);
        float4 bv = *(const float4*)(be + c4);
        float4 y;
        y.x = fmaxf(dx * rs * gv.x + bv.x, 0.f);
        y.y = fmaxf(dy * rs * gv.y + bv.y, 0.f);
        y.z = fmaxf(dz * rs * gv.z + bv.z, 0.f);
        y.w = fmaxf(dw * rs * gv.w + bv.w, 0.f);
        *(float4*)&s_h[w][c4] = y;
    }
    __syncthreads();
    int cl = t & 127, half = t >> 7;
    int gc = cq * 128 + cl;
    const float* wbase; float bias; float* obase; float* sdst; int oc;
    if (gc < C2) { wbase = wl + gc; bias = bl[gc]; obase = xl; sdst = sl; oc = gc; }
    else         { wbase = wr + gc - C2; bias = br[gc - C2]; obase = xr; sdst = sr; oc = gc - C2; }
    int ra = half * 2, rb = ra + 1;
    float a0 = bias, a1 = bias;
#pragma unroll 8
    for (int k = 0; k < C1; k++) {
        float wv = wbase[(size_t)k * C2];
        a0 += s_h[ra][k] * wv;
        a1 += s_h[rb][k] * wv;
    }
    obase[(size_t)(row0 + ra) * C2 + oc] = a0;
    obase[(size_t)(row0 + rb) * C2 + oc] = a1;
    float attv = att[oc];
    float s0 = bf_sum(attv * a0) * 0.6f;
    float s1 = bf_sum(attv * a1) * 0.6f;
    if (lane == 0) {
        int h = oc >> 6;
        int rwa = row0 + ra, rwb = row0 + rb;
        sdst[(h * BB + (rwa >> 9)) * NN + (rwa & 511)] = s0;
        sdst[(h * BB + (rwb >> 9)) * NN + (rwb & 511)] = s1;
    }
}

// --- GATv2 attention. Block = (16 i, 64 j, h, b). Grid (256,4,2) = 2048
// blocks. __launch_bounds__(256,4): 128-VGPR cap -> >=4 waves/SIMD can
// mount (LDS 20.3KB allows 7 blocks/CU). Single j-phase (j = j0+lane).
// xbuf [64][64] XOR-swizzled via global_load_lds. Aggregate: RUNTIME outer
// loop (SGPR counter), inner 8 unrolled, readlane with SGPR lane index.
__global__ __launch_bounds__(256, 4) void attn_k(const float* __restrict__ xl,
        const float* __restrict__ xr, const float* __restrict__ att,
        const u64* __restrict__ mask64,
        const float* __restrict__ sl, const float* __restrict__ sr,
        float* __restrict__ pagg, float* __restrict__ plsum) {
    __shared__ __align__(16) float xbuf[64 * 64];
    __shared__ __align__(16) float s_xr[16][DH];
    __shared__ __align__(16) float s_att[DH];    // prescaled by 0.4

    int bx = blockIdx.x;
    int it = bx >> 3, jc = bx & 7;
    int h = blockIdx.y, b = blockIdx.z;
    int t = threadIdx.x, lane = t & 63;
    int wu = __builtin_amdgcn_readfirstlane(t >> 6);   // wave id in SGPR
    int i0 = it * 16, j0 = jc * 64;

    const float* xlbase = xl + (size_t)b * NN * C1 + h * DH;

    // ---- stage xbuf: wave wu stages rows [wu*16, wu*16+16), 4 x 1KB DMAs ----
    {
        int jr0 = wu * 16;
#pragma unroll
        for (int k = 0; k < 4; k++) {
            int jrow = jr0 + k * 4 + (lane >> 4);
            int dslot = (lane & 15) ^ (jrow & 7);          // pre-swizzled source
            const float* gp = xlbase + (size_t)(j0 + jrow) * C1 + (dslot << 2);
            gload_lds16(gp, &xbuf[(jr0 + k * 4) * 64]);    // wave-uniform dest
        }
    }
    {   // 16 xr rows -> LDS
        int row = t >> 4, d4 = (t & 15) << 2;
        *(float4*)&s_xr[row][d4] =
            *(const float4*)(xr + (size_t)(b * NN + i0 + row) * C1 + h * DH + d4);
    }
    if (t < DH) s_att[t] = att[h * DH + t] * 0.4f;

    // ---- pre-hoisted uniforms (all OUTSIDE the loops) ----
    int rbase = (h * BB + b) * NN;
    float rsr0 = sr[rbase + i0 + wu * 4 + 0];
    float rsr1 = sr[rbase + i0 + wu * 4 + 1];
    float rsr2 = sr[rbase + i0 + wu * 4 + 2];
    float rsr3 = sr[rbase + i0 + wu * 4 + 3];
    const u64* mb_ = mask64 + (size_t)(i0 + wu * 4) * 8 + jc;
    u64 m0 = mb_[0], m1 = mb_[8], m2 = mb_[16], m3 = mb_[24];
    float slv = sl[rbase + j0 + lane];

    __syncthreads();

    int swz = lane & 7;

    // ---- scores: j = j0 + lane, rows wu*4 .. wu*4+3 ----
    float a0 = 0.f, a1 = 0.f, a2 = 0.f, a3 = 0.f;
    const float* xrow = &xbuf[lane * 64];
#pragma unroll 4
    for (int dc = 0; dc < 16; dc++) {
        int so = (dc ^ swz) << 2;
        float4 xv = *(const float4*)(xrow + so);
        float4 av = *(const float4*)&s_att[dc << 2];
        float4 r0 = *(const float4*)&s_xr[wu * 4 + 0][dc << 2];
        float4 r1 = *(const float4*)&s_xr[wu * 4 + 1][dc << 2];
        float4 r2 = *(const float4*)&s_xr[wu * 4 + 2][dc << 2];
        float4 r3 = *(const float4*)&s_xr[wu * 4 + 3][dc << 2];
        a0 = fmaf(av.x, fabsf(xv.x + r0.x), a0); a0 = fmaf(av.y, fabsf(xv.y + r0.y), a0);
        a0 = fmaf(av.z, fabsf(xv.z + r0.z), a0); a0 = fmaf(av.w, fabsf(xv.w + r0.w), a0);
        a1 = fmaf(av.x, fabsf(xv.x + r1.x), a1); a1 = fmaf(av.y, fabsf(xv.y + r1.y), a1);
        a1 = fmaf(av.z, fabsf(xv.z + r1.z), a1); a1 = fmaf(av.w, fabsf(xv.w + r1.w), a1);
        a2 = fmaf(av.x, fabsf(xv.x + r2.x), a2); a2 = fmaf(av.y, fabsf(xv.y + r2.y), a2);
        a2 = fmaf(av.z, fabsf(xv.z + r2.z), a2); a2 = fmaf(av.w, fabsf(xv.w + r2.w), a2);
        a3 = fmaf(av.x, fabsf(xv.x + r3.x), a3); a3 = fmaf(av.y, fabsf(xv.y + r3.y), a3);
        a3 = fmaf(av.z, fabsf(xv.z + r3.z), a3); a3 = fmaf(av.w, fabsf(xv.w + r3.w), a3);
    }

    // ---- p (registers only; s_att prescale carries the 0.4) ----
    float p0 = ((m0 >> lane) & 1ull) ? __expf(slv + rsr0 + a0) : 0.f;
    float p1 = ((m1 >> lane) & 1ull) ? __expf(slv + rsr1 + a1) : 0.f;
    float p2 = ((m2 >> lane) & 1ull) ? __expf(slv + rsr2 + a2) : 0.f;
    float p3 = ((m3 >> lane) & 1ull) ? __expf(slv + rsr3 + a3) : 0.f;

    // ---- aggregate: lane = d; out[r] += sum_j p[r][j]*xbuf[j][d].
    // Outer loop RUNTIME (SGPR counter -> readlane SGPR lane index);
    // inner 8 unrolled. Keeps live-register peak ~100 for the 128 cap. ----
    int cc = lane >> 2, e = lane & 3;
    float out0 = 0.f, out1 = 0.f, out2 = 0.f, out3 = 0.f;
#pragma unroll 1
    for (int g = 0; g < 8; g++) {
        int rowb = g * 8;           // wave-uniform -> SGPR
#pragma unroll
        for (int u = 0; u < 8; u++) {
            float xb = xbuf[(rowb + u) * 64 + (((cc ^ u) << 2) | e)];
            int li = rowb + u;      // SGPR + const
            out0 += rdlane(p0, li) * xb;
            out1 += rdlane(p1, li) * xb;
            out2 += rdlane(p2, li) * xb;
            out3 += rdlane(p3, li) * xb;
        }
    }

    float l0 = bf_sum(p0), l1 = bf_sum(p1), l2 = bf_sum(p2), l3 = bf_sum(p3);
    size_t ob = ((size_t)jc * BB * NN + b * NN + i0 + wu * 4) * C1 + h * DH + lane;
    pagg[ob]          = out0;
    pagg[ob + C1]     = out1;
    pagg[ob + 2 * C1] = out2;
    pagg[ob + 3 * C1] = out3;
    if (lane == 0) {
        float* pl = plsum + ((size_t)jc * HH * BB + h * BB + b) * NN + i0 + wu * 4;
        pl[0] = l0; pl[1] = l1; pl[2] = l2; pl[3] = l3;
    }
}

// --- combine partials + final LayerNorm, wave-per-row ---
__global__ __launch_bounds__(256) void ln2_k(const float* __restrict__ pagg,
        const float* __restrict__ plsum, const float* __restrict__ abias,
        const float* __restrict__ g, const float* __restrict__ be,
        float* __restrict__ outp) {
    int t = threadIdx.x, lane = t & 63, w = t >> 6;
    int rgb = blockIdx.x * 4 + w;
    int bb = rgb >> 9, ii = rgb & 511;
    int c4 = lane << 2, hh = lane >> 4;
    float vx = 0.f, vy = 0.f, vz = 0.f, vw = 0.f, l = 0.f;
#pragma unroll
    for (int jc = 0; jc < NJC; jc++) {
        float4 a = *(const float4*)(pagg + ((size_t)jc * BB * NN + rgb) * C1 + c4);
        vx += a.x; vy += a.y; vz += a.z; vw += a.w;
        l += plsum[((size_t)jc * HH * BB + hh * BB + bb) * NN + ii];
    }
    float inv = 1.f / l;
    float4 bi = *(const float4*)(abias + c4);
    vx = vx * inv + bi.x; vy = vy * inv + bi.y;
    vz = vz * inv + bi.z; vw = vw * inv + bi.w;
    float mu = bf_sum(vx + vy + vz + vw) * (1.f / 256.f);
    float dx = vx - mu, dy = vy - mu, dz = vz - mu, dw = vw - mu;
    float var = bf_sum(dx * dx + dy * dy + dz * dz + dw * dw) * (1.f / 256.f);
    float rs = rsqrtf(var + LEPS);
    float4 gv = *(const float4*)(g + c4);
    float4 bv = *(const float4*)(be + c4);
    float4 y;
    y.x = dx * rs * gv.x + bv.x;
    y.y = dy * rs * gv.y + bv.y;
    y.z = dz * rs * gv.z + bv.z;
    y.w = dw * rs * gv.w + bv.w;
    *(float4*)(outp + (size_t)rgb * C1 + c4) = y;
}

extern "C" void kernel_launch(void* const* d_in, const int* in_sizes, int n_in,
                              void* d_out, int out_size, void* d_ws, size_t ws_size,
                              hipStream_t stream) {
    const float* x    = (const float*)d_in[0];
    const float* emb  = (const float*)d_in[1];
    const float* w1l  = (const float*)d_in[2];
    const float* b1l  = (const float*)d_in[3];
    const float* w1r  = (const float*)d_in[4];
    const float* b1r  = (const float*)d_in[5];
    const float* att1 = (const float*)d_in[6];
    const float* bia1 = (const float*)d_in[7];
    const float* g1   = (const float*)d_in[8];
    const float* be1  = (const float*)d_in[9];
    const float* w2l  = (const float*)d_in[10];
    const float* b2l  = (const float*)d_in[11];
    const float* w2r  = (const float*)d_in[12];
    const float* b2r  = (const float*)d_in[13];
    const float* att2 = (const float*)d_in[14];
    const float* bia2 = (const float*)d_in[15];
    const float* g2   = (const float*)d_in[16];
    const float* be2  = (const float*)d_in[17];

    char* w = (char*)d_ws;
    float* xl    = (float*)w; w += (size_t)BB * NN * C1 * 4;
    float* xr    = (float*)w; w += (size_t)BB * NN * C1 * 4;
    float* pagg  = (float*)w; w += (size_t)NJC * BB * NN * C1 * 4;
    u64* mask64  = (u64*)w;   w += (size_t)NN * 8 * 8;
    float* plsum = (float*)w; w += (size_t)NJC * HH * BB * NN * 4;
    float* sl    = (float*)w; w += (size_t)HH * BB * NN * 4;
    float* sr    = (float*)w; w += (size_t)HH * BB * NN * 4;

    mp1_k<<<dim3(1280), 256, 0, stream>>>(x, w1l, b1l, w1r, b1r, att1, emb,
                                          xl, xr, sl, sr, mask64);
    attn_k<<<dim3((NN / 16) * NJC, HH, BB), 256, 0, stream>>>(xl, xr, att1, mask64, sl, sr, pagg, plsum);
    projln_k<<<dim3(BB * NN / 4, 4), 256, 0, stream>>>(pagg, plsum, bia1, g1, be1,
                                                       w2l, b2l, w2r, b2r, att2, xl, xr, sl, sr);
    attn_k<<<dim3((NN / 16) * NJC, HH, BB), 256, 0, stream>>>(xl, xr, att2, mask64, sl, sr, pagg, plsum);
    ln2_k<<<BB * NN / 4, 256, 0, stream>>>(pagg, plsum, bia2, g2, be2, (float*)d_out);
}

// Round 12
// 158.946 us; speedup vs baseline: 1.1006x; 1.1006x over previous
//
#include <hip/hip_runtime.h>

// GATv2 x2 + LayerNorm, B=2 N=512 DIN=32 DH=DOUT=64 H=4. fp32 in/out.
// R22 = R18 base + uniform-operand DS elimination in attn. The invariant
// across 7 flat rounds: score loop issued 5 wave-UNIFORM ds_read_b128
// (av, r0..r3) per dc iter = 80 of 112 b128/wave on the shared per-CU
// LDS pipe (~14us/CU issue floor). Now att + 4 xr rows live as per-lane
// VGPRs (att_v, xrv0..3); score fetches elements via readlane (const
// idx) -> SGPR operands (legal: 1 SGPR/VALU op; abs is a free modifier).
// DS/wave 2090 -> ~1130 cy. s_xr/s_att deleted; LDS = xbuf 32KB.
// R21's (256,4) cap + R20's NJC=8 both regressed -> reverted to R18 form.

#define BB   2
#define NN   512
#define DIN  32
#define DH   64
#define HH   4
#define C1   256
#define C2   256
#define NJC  4     // j-chunks (128 j each)
#define LEPS 1e-5f

typedef unsigned long long u64;

__device__ __forceinline__ float bf_sum(float v) {
#pragma unroll
    for (int o = 32; o > 0; o >>= 1) v += __shfl_xor(v, o, 64);
    return v;
}

__device__ __forceinline__ void gload_lds16(const float* g, float* l) {
    __builtin_amdgcn_global_load_lds(
        (const __attribute__((address_space(1))) void*)g,
        (__attribute__((address_space(3))) void*)l, 16, 0, 0);
}

__device__ __forceinline__ float rdlane(float v, int l) {
    return __int_as_float(__builtin_amdgcn_readlane(__float_as_int(v), l));
}

// --- merged: blocks 0..1023 = proj1 (+fused sl/sr); 1024..1279 = mask ---
__global__ __launch_bounds__(256) void mp1_k(const float* __restrict__ x,
        const float* __restrict__ wl, const float* __restrict__ bl,
        const float* __restrict__ wr, const float* __restrict__ br,
        const float* __restrict__ att, const float* __restrict__ emb,
        float* __restrict__ xl, float* __restrict__ xr,
        float* __restrict__ sl, float* __restrict__ sr,
        u64* __restrict__ mask64) {
    __shared__ __align__(16) float s_ei[16][DH];
    __shared__ float ebuf[64][DH + 1];
    __shared__ float s_x[4][DIN];
    int bx = blockIdx.x;
    int t = threadIdx.x, lane = t & 63;

    if (bx >= 1024) {   // ---- mask role: 256 blocks, 16i x 64j tile ----
        int idx = bx - 1024, it = idx >> 3, jq = idx & 7;
        int iq = t >> 6, j0 = jq * 64;
        {
            int row = t >> 4, d4 = (t & 15) << 2;
            *(float4*)&s_ei[row][d4] = *(const float4*)(emb + (it * 16 + row) * DH + d4);
        }
#pragma unroll
        for (int k = 0; k < 4; k++) {
            int i2 = k * 256 + t, jl = i2 >> 4, d4 = (i2 & 15) << 2;
            float4 v = *(const float4*)(emb + (j0 + jl) * DH + d4);
            ebuf[jl][d4] = v.x; ebuf[jl][d4 + 1] = v.y;
            ebuf[jl][d4 + 2] = v.z; ebuf[jl][d4 + 3] = v.w;
        }
        __syncthreads();
        float acc[4] = {0.f, 0.f, 0.f, 0.f};
        for (int dc = 0; dc < 16; dc++) {
            int d = dc * 4;
            float e0 = ebuf[lane][d], e1 = ebuf[lane][d + 1];
            float e2 = ebuf[lane][d + 2], e3 = ebuf[lane][d + 3];
#pragma unroll
            for (int r = 0; r < 4; r++) {
                float4 iv = *(const float4*)&s_ei[iq * 4 + r][d];
                acc[r] += iv.x * e0 + iv.y * e1 + iv.z * e2 + iv.w * e3;
            }
        }
        int jg = j0 + lane;
#pragma unroll
        for (int r = 0; r < 4; r++) {
            int ig = it * 16 + iq * 4 + r;
            u64 bal = __ballot(acc[r] != 0.f || ig == jg);
            if (lane == 0) mask64[ig * 8 + jq] = bal;
        }
        return;
    }

    // ---- proj1 role ----
    int row0 = (bx >> 2) * 4, cq = bx & 3;
    if (t < 128) s_x[t >> 5][t & 31] = x[(row0 + (t >> 5)) * DIN + (t & 31)];
    __syncthreads();
    int cl = t & 127, half = t >> 7;
    int gc = cq * 128 + cl;
    const float* wbase; float bias; float* obase; float* sdst; int oc;
    if (gc < C1) { wbase = wl + gc; bias = bl[gc]; obase = xl; sdst = sl; oc = gc; }
    else         { wbase = wr + gc - C1; bias = br[gc - C1]; obase = xr; sdst = sr; oc = gc - C1; }
    int ra = half * 2, rb = ra + 1;
    float a0 = bias, a1 = bias;
#pragma unroll
    for (int k = 0; k < DIN; k++) {
        float wv = wbase[(size_t)k * C1];
        a0 += s_x[ra][k] * wv;
        a1 += s_x[rb][k] * wv;
    }
    obase[(size_t)(row0 + ra) * C1 + oc] = a0;
    obase[(size_t)(row0 + rb) * C1 + oc] = a1;
    float attv = att[oc];
    float s0 = bf_sum(attv * a0) * 0.6f;
    float s1 = bf_sum(attv * a1) * 0.6f;
    if (lane == 0) {
        int h = oc >> 6;
        int rwa = row0 + ra, rwb = row0 + rb;
        sdst[(h * BB + (rwa >> 9)) * NN + (rwa & 511)] = s0;
        sdst[(h * BB + (rwb >> 9)) * NN + (rwb & 511)] = s1;
    }
}

// --- combine partials + LN(g,be)+ReLU + proj2 + sl/sr ---
__global__ __launch_bounds__(256) void projln_k(const float* __restrict__ pagg,
        const float* __restrict__ plsum, const float* __restrict__ abias,
        const float* __restrict__ g, const float* __restrict__ be,
        const float* __restrict__ wl, const float* __restrict__ bl,
        const float* __restrict__ wr, const float* __restrict__ br,
        const float* __restrict__ att,
        float* __restrict__ xl, float* __restrict__ xr,
        float* __restrict__ sl, float* __restrict__ sr) {
    __shared__ __align__(16) float s_h[4][C1];
    int t = threadIdx.x, lane = t & 63, w = t >> 6;
    int row0 = blockIdx.x * 4, cq = blockIdx.y;
    {
        int rgb = row0 + w;
        int bb = rgb >> 9, ii = rgb & 511;
        int c4 = lane << 2, hh = lane >> 4;
        float vx = 0.f, vy = 0.f, vz = 0.f, vw = 0.f, l = 0.f;
#pragma unroll
        for (int jc = 0; jc < NJC; jc++) {
            float4 a = *(const float4*)(pagg + ((size_t)jc * BB * NN + rgb) * C1 + c4);
            vx += a.x; vy += a.y; vz += a.z; vw += a.w;
            l += plsum[((size_t)jc * HH * BB + hh * BB + bb) * NN + ii];
        }
        float inv = 1.f / l;
        float4 bi = *(const float4*)(abias + c4);
        vx = vx * inv + bi.x; vy = vy * inv + bi.y;
        vz = vz * inv + bi.z; vw = vw * inv + bi.w;
        float mu = bf_sum(vx + vy + vz + vw) * (1.f / 256.f);
        float dx = vx - mu, dy = vy - mu, dz = vz - mu, dw = vw - mu;
        float var = bf_sum(dx * dx + dy * dy + dz * dz + dw * dw) * (1.f / 256.f);
        float rs = rsqrtf(var + LEPS);
        float4 gv = *(const float4*)(g + c4);
        float4 bv = *(const float4*)(be + c4);
        float4 y;
        y.x = fmaxf(dx * rs * gv.x + bv.x, 0.f);
        y.y = fmaxf(dy * rs * gv.y + bv.y, 0.f);
        y.z = fmaxf(dz * rs * gv.z + bv.z, 0.f);
        y.w = fmaxf(dw * rs * gv.w + bv.w, 0.f);
        *(float4*)&s_h[w][c4] = y;
    }
    __syncthreads();
    int cl = t & 127, half = t >> 7;
    int gc = cq * 128 + cl;
    const float* wbase; float bias; float* obase; float* sdst; int oc;
    if (gc < C2) { wbase = wl + gc; bias = bl[gc]; obase = xl; sdst = sl; oc = gc; }
    else         { wbase = wr + gc - C2; bias = br[gc - C2]; obase = xr; sdst = sr; oc = gc - C2; }
    int ra = half * 2, rb = ra + 1;
    float a0 = bias, a1 = bias;
#pragma unroll 8
    for (int k = 0; k < C1; k++) {
        float wv = wbase[(size_t)k * C2];
        a0 += s_h[ra][k] * wv;
        a1 += s_h[rb][k] * wv;
    }
    obase[(size_t)(row0 + ra) * C2 + oc] = a0;
    obase[(size_t)(row0 + rb) * C2 + oc] = a1;
    float attv = att[oc];
    float s0 = bf_sum(attv * a0) * 0.6f;
    float s1 = bf_sum(attv * a1) * 0.6f;
    if (lane == 0) {
        int h = oc >> 6;
        int rwa = row0 + ra, rwb = row0 + rb;
        sdst[(h * BB + (rwa >> 9)) * NN + (rwa & 511)] = s0;
        sdst[(h * BB + (rwb >> 9)) * NN + (rwb & 511)] = s1;
    }
}

// --- GATv2 attention. Block = (16 i, 128 j, h, b). 1024 blocks.
// xbuf [128][64] XOR-swizzled via global_load_lds (only LDS buffer, 32KB).
// att + 4 xr rows held as per-lane VGPRs; score loop fetches their
// elements via readlane (const idx -> SGPR operand). DS pipe now carries
// only per-lane xv reads (32 b128) + aggregate (128 b32) per wave.
__global__ __launch_bounds__(256) void attn_k(const float* __restrict__ xl,
        const float* __restrict__ xr, const float* __restrict__ att,
        const u64* __restrict__ mask64,
        const float* __restrict__ sl, const float* __restrict__ sr,
        float* __restrict__ pagg, float* __restrict__ plsum) {
    __shared__ __align__(16) float xbuf[128 * 64];

    int bx = blockIdx.x;
    int it = bx >> 2, jc = bx & 3;
    int h = blockIdx.y, b = blockIdx.z;
    int t = threadIdx.x, lane = t & 63;
    int wu = __builtin_amdgcn_readfirstlane(t >> 6);   // wave id in SGPR
    int i0 = it * 16, j0 = jc * 128;

    const float* xlbase = xl + (size_t)b * NN * C1 + h * DH;

    // ---- stage xbuf: wave wu stages rows [wu*32, wu*32+32), 8 x 1KB DMAs ----
    {
        int jr0 = wu * 32;
#pragma unroll
        for (int k = 0; k < 8; k++) {
            int jrow = jr0 + k * 4 + (lane >> 4);
            int dslot = (lane & 15) ^ (jrow & 7);          // pre-swizzled source
            const float* gp = xlbase + (size_t)(j0 + jrow) * C1 + (dslot << 2);
            gload_lds16(gp, &xbuf[(jr0 + k * 4) * 64]);    // wave-uniform dest
        }
    }

    // ---- per-lane VGPR copies of the wave-uniform operand vectors ----
    float att_v = att[h * DH + lane] * 0.4f;                         // a_d, d=lane
    const float* xrb = xr + (size_t)(b * NN + i0 + wu * 4) * C1 + h * DH;
    float xrv0 = xrb[lane];
    float xrv1 = xrb[C1 + lane];
    float xrv2 = xrb[2 * C1 + lane];
    float xrv3 = xrb[3 * C1 + lane];

    // ---- pre-hoisted uniforms (all OUTSIDE the loops) ----
    int rbase = (h * BB + b) * NN;
    float rsr0 = sr[rbase + i0 + wu * 4 + 0];
    float rsr1 = sr[rbase + i0 + wu * 4 + 1];
    float rsr2 = sr[rbase + i0 + wu * 4 + 2];
    float rsr3 = sr[rbase + i0 + wu * 4 + 3];
    const u64* mb_ = mask64 + (size_t)(i0 + wu * 4) * 8 + jc * 2;
    u64 m00 = mb_[0],  m01 = mb_[1];
    u64 m10 = mb_[8],  m11 = mb_[9];
    u64 m20 = mb_[16], m21 = mb_[17];
    u64 m30 = mb_[24], m31 = mb_[25];
    unsigned mb0 = (unsigned)((m00 >> lane) & 1ull) | ((unsigned)((m01 >> lane) & 1ull) << 1);
    unsigned mb1 = (unsigned)((m10 >> lane) & 1ull) | ((unsigned)((m11 >> lane) & 1ull) << 1);
    unsigned mb2 = (unsigned)((m20 >> lane) & 1ull) | ((unsigned)((m21 >> lane) & 1ull) << 1);
    unsigned mb3 = (unsigned)((m30 >> lane) & 1ull) | ((unsigned)((m31 >> lane) & 1ull) << 1);
    float slv0 = sl[rbase + j0 + lane];
    float slv1 = sl[rbase + j0 + 64 + lane];

    __syncthreads();

    int swz = lane & 7;

    // ---- scores: dc-outer, both phases (j = lane and 64+lane), 4 i-rows.
    // Uniform elements via readlane (SGPR); only xv comes from LDS. ----
    float a00=0,a01=0,a02=0,a03=0;   // phase 0 (j=lane), rows 0..3
    float a10=0,a11=0,a12=0,a13=0;   // phase 1 (j=64+lane)
    const float* xr0 = &xbuf[lane * 64];
    const float* xr1 = &xbuf[(64 + lane) * 64];
#pragma unroll
    for (int dc = 0; dc < 16; dc++) {
        int so = (dc ^ swz) << 2;
        float4 xv0 = *(const float4*)(xr0 + so);
        float4 xv1 = *(const float4*)(xr1 + so);
#pragma unroll
        for (int e = 0; e < 4; e++) {
            int idx = dc * 4 + e;                       // compile-time constant
            float sav = rdlane(att_v, idx);
            float sr0 = rdlane(xrv0, idx);
            float sr1 = rdlane(xrv1, idx);
            float sr2 = rdlane(xrv2, idx);
            float sr3 = rdlane(xrv3, idx);
            float x0 = (e == 0) ? xv0.x : (e == 1) ? xv0.y : (e == 2) ? xv0.z : xv0.w;
            float x1 = (e == 0) ? xv1.x : (e == 1) ? xv1.y : (e == 2) ? xv1.z : xv1.w;
            a00 = fmaf(sav, fabsf(x0 + sr0), a00);
            a01 = fmaf(sav, fabsf(x0 + sr1), a01);
            a02 = fmaf(sav, fabsf(x0 + sr2), a02);
            a03 = fmaf(sav, fabsf(x0 + sr3), a03);
            a10 = fmaf(sav, fabsf(x1 + sr0), a10);
            a11 = fmaf(sav, fabsf(x1 + sr1), a11);
            a12 = fmaf(sav, fabsf(x1 + sr2), a12);
            a13 = fmaf(sav, fabsf(x1 + sr3), a13);
        }
    }

    // ---- p (registers only) ----
    float p00 = (mb0 & 1u) ? __expf(slv0 + rsr0 + a00) : 0.f;
    float p01 = (mb1 & 1u) ? __expf(slv0 + rsr1 + a01) : 0.f;
    float p02 = (mb2 & 1u) ? __expf(slv0 + rsr2 + a02) : 0.f;
    float p03 = (mb3 & 1u) ? __expf(slv0 + rsr3 + a03) : 0.f;
    float p10 = (mb0 & 2u) ? __expf(slv1 + rsr0 + a10) : 0.f;
    float p11 = (mb1 & 2u) ? __expf(slv1 + rsr1 + a11) : 0.f;
    float p12 = (mb2 & 2u) ? __expf(slv1 + rsr2 + a12) : 0.f;
    float p13 = (mb3 & 2u) ? __expf(slv1 + rsr3 + a13) : 0.f;
    float ls0 = p00 + p10, ls1 = p01 + p11, ls2 = p02 + p12, ls3 = p03 + p13;

    // ---- aggregate: lane = d; out[r] += sum_j p[r][j]*xbuf[j][d].
    // 16 ds_read_b32 batched per group; p via const-idx readlane. ----
    int cc = lane >> 2, e = lane & 3;
    float out0 = 0.f, out1 = 0.f, out2 = 0.f, out3 = 0.f;
#pragma unroll
    for (int g = 0; g < 8; g++) {
        float xb[16];
#pragma unroll
        for (int u = 0; u < 16; u++) {
            int row = g * 16 + u;
            xb[u] = xbuf[row * 64 + (((cc ^ (u & 7)) << 2) | e)];
        }
#pragma unroll
        for (int u = 0; u < 16; u++) {
            int li = (g & 3) * 16 + u;
            float q0, q1, q2, q3;
            if (g < 4) { q0 = rdlane(p00, li); q1 = rdlane(p01, li);
                         q2 = rdlane(p02, li); q3 = rdlane(p03, li); }
            else       { q0 = rdlane(p10, li); q1 = rdlane(p11, li);
                         q2 = rdlane(p12, li); q3 = rdlane(p13, li); }
            out0 += q0 * xb[u]; out1 += q1 * xb[u];
            out2 += q2 * xb[u]; out3 += q3 * xb[u];
        }
    }

    float l0 = bf_sum(ls0), l1 = bf_sum(ls1), l2 = bf_sum(ls2), l3 = bf_sum(ls3);
    size_t ob = ((size_t)jc * BB * NN + b * NN + i0 + wu * 4) * C1 + h * DH + lane;
    pagg[ob]          = out0;
    pagg[ob + C1]     = out1;
    pagg[ob + 2 * C1] = out2;
    pagg[ob + 3 * C1] = out3;
    if (lane == 0) {
        float* pl = plsum + ((size_t)jc * HH * BB + h * BB + b) * NN + i0 + wu * 4;
        pl[0] = l0; pl[1] = l1; pl[2] = l2; pl[3] = l3;
    }
}

// --- combine partials + final LayerNorm, wave-per-row ---
__global__ __launch_bounds__(256) void ln2_k(const float* __restrict__ pagg,
        const float* __restrict__ plsum, const float* __restrict__ abias,
        const float* __restrict__ g, const float* __restrict__ be,
        float* __restrict__ outp) {
    int t = threadIdx.x, lane = t & 63, w = t >> 6;
    int rgb = blockIdx.x * 4 + w;
    int bb = rgb >> 9, ii = rgb & 511;
    int c4 = lane << 2, hh = lane >> 4;
    float vx = 0.f, vy = 0.f, vz = 0.f, vw = 0.f, l = 0.f;
#pragma unroll
    for (int jc = 0; jc < NJC; jc++) {
        float4 a = *(const float4*)(pagg + ((size_t)jc * BB * NN + rgb) * C1 + c4);
        vx += a.x; vy += a.y; vz += a.z; vw += a.w;
        l += plsum[((size_t)jc * HH * BB + hh * BB + bb) * NN + ii];
    }
    float inv = 1.f / l;
    float4 bi = *(const float4*)(abias + c4);
    vx = vx * inv + bi.x; vy = vy * inv + bi.y;
    vz = vz * inv + bi.z; vw = vw * inv + bi.w;
    float mu = bf_sum(vx + vy + vz + vw) * (1.f / 256.f);
    float dx = vx - mu, dy = vy - mu, dz = vz - mu, dw = vw - mu;
    float var = bf_sum(dx * dx + dy * dy + dz * dz + dw * dw) * (1.f / 256.f);
    float rs = rsqrtf(var + LEPS);
    float4 gv = *(const float4*)(g + c4);
    float4 bv = *(const float4*)(be + c4);
    float4 y;
    y.x = dx * rs * gv.x + bv.x;
    y.y = dy * rs * gv.y + bv.y;
    y.z = dz * rs * gv.z + bv.z;
    y.w = dw * rs * gv.w + bv.w;
    *(float4*)(outp + (size_t)rgb * C1 + c4) = y;
}

extern "C" void kernel_launch(void* const* d_in, const int* in_sizes, int n_in,
                              void* d_out, int out_size, void* d_ws, size_t ws_size,
                              hipStream_t stream) {
    const float* x    = (const float*)d_in[0];
    const float* emb  = (const float*)d_in[1];
    const float* w1l  = (const float*)d_in[2];
    const float* b1l  = (const float*)d_in[3];
    const float* w1r  = (const float*)d_in[4];
    const float* b1r  = (const float*)d_in[5];
    const float* att1 = (const float*)d_in[6];
    const float* bia1 = (const float*)d_in[7];
    const float* g1   = (const float*)d_in[8];
    const float* be1  = (const float*)d_in[9];
    const float* w2l  = (const float*)d_in[10];
    const float* b2l  = (const float*)d_in[11];
    const float* w2r  = (const float*)d_in[12];
    const float* b2r  = (const float*)d_in[13];
    const float* att2 = (const float*)d_in[14];
    const float* bia2 = (const float*)d_in[15];
    const float* g2   = (const float*)d_in[16];
    const float* be2  = (const float*)d_in[17];

    char* w = (char*)d_ws;
    float* xl    = (float*)w; w += (size_t)BB * NN * C1 * 4;
    float* xr    = (float*)w; w += (size_t)BB * NN * C1 * 4;
    float* pagg  = (float*)w; w += (size_t)NJC * BB * NN * C1 * 4;
    u64* mask64  = (u64*)w;   w += (size_t)NN * 8 * 8;
    float* plsum = (float*)w; w += (size_t)NJC * HH * BB * NN * 4;
    float* sl    = (float*)w; w += (size_t)HH * BB * NN * 4;
    float* sr    = (float*)w; w += (size_t)HH * BB * NN * 4;

    mp1_k<<<dim3(1280), 256, 0, stream>>>(x, w1l, b1l, w1r, b1r, att1, emb,
                                          xl, xr, sl, sr, mask64);
    attn_k<<<dim3((NN / 16) * NJC, HH, BB), 256, 0, stream>>>(xl, xr, att1, mask64, sl, sr, pagg, plsum);
    projln_k<<<dim3(BB * NN / 4, 4), 256, 0, stream>>>(pagg, plsum, bia1, g1, be1,
                                                       w2l, b2l, w2r, b2r, att2, xl, xr, sl, sr);
    attn_k<<<dim3((NN / 16) * NJC, HH, BB), 256, 0, stream>>>(xl, xr, att2, mask64, sl, sr, pagg, plsum);
    ln2_k<<<BB * NN / 4, 256, 0, stream>>>(pagg, plsum, bia2, g2, be2, (float*)d_out);
}